// Round 7
// baseline (300.908 us; speedup 1.0000x reference)
//
#include <hip/hip_runtime.h>
#include <hip/hip_bf16.h>
#include <math.h>

typedef __attribute__((ext_vector_type(8))) __bf16 bf16x8;
typedef __attribute__((ext_vector_type(4))) float f32x4;

#define IN_DIM 2048
#define NH1 128
#define NH2 64
#define KDIM 1024

__device__ inline f32x4 mfma16(bf16x8 a, bf16x8 b, f32x4 c) {
    return __builtin_amdgcn_mfma_f32_16x16x32_bf16(a, b, c, 0, 0, 0);
}

__device__ inline void gld16(const void* g, void* l) {
    __builtin_amdgcn_global_load_lds(
        (const __attribute__((address_space(1))) void*)g,
        (__attribute__((address_space(3))) void*)l, 16, 0, 0);
}

// ---------------------------------------------------------------------------
// prep: permute W1/W2 into MFMA-fragment order (bf16), pack basis rows with
// c_j = head_w[j] * exp(-||b_j||^2).
// Fragment convention (A and B identical): within a 32-k x 16-col tile,
// lane l, elem e  ->  k = (l>>4)*8 + e , col/row = l&15.
// ---------------------------------------------------------------------------
__global__ void prep_kernel(const float* __restrict__ W1,
                            const float* __restrict__ W2,
                            const float* __restrict__ basis,
                            const float* __restrict__ head_w,
                            __bf16* __restrict__ w1f,
                            __bf16* __restrict__ w2f,
                            float* __restrict__ bp) {
    int idx = blockIdx.x * 256 + threadIdx.x;   // 0 .. 262143
    if (idx < IN_DIM * NH1) {
        int ks = idx >> 12;
        int rem = idx & 4095;
        int c = rem >> 9;
        int q = rem & 511;
        int l = q >> 3, e = q & 7;
        int k = ks * 32 + ((l >> 4) << 3) + e;
        int col = (c << 4) + (l & 15);
        w1f[idx] = (__bf16)W1[k * NH1 + col];
    }
    if (idx < NH1 * NH2) {
        int cb = idx >> 9;
        int c2 = cb >> 2, kb = cb & 3;
        int q = idx & 511;
        int l = q >> 3, e = q & 7;
        int k = kb * 32 + ((l >> 4) << 3) + e;
        int col = (c2 << 4) + (l & 15);
        w2f[idx] = (__bf16)W2[k * NH2 + col];
    }
    if (idx < KDIM) {
        const float* b = basis + idx * 5;
        float n2 = b[0]*b[0] + b[1]*b[1] + b[2]*b[2] + b[3]*b[3] + b[4]*b[4];
        float* o = bp + idx * 8;
        o[0] = b[0]; o[1] = b[1]; o[2] = b[2]; o[3] = b[3]; o[4] = b[4];
        o[5] = 1.0f;
        o[6] = head_w[idx] * expf(-n2);   // gamma = 1
        o[7] = 0.0f;
    }
}

// ---------------------------------------------------------------------------
// fused main, DRAM-burst-oriented:
//   block = 2 waves, BM=32 rows; 8 phases, each staging 32 rows x 1 KB
//   CONTIGUOUS x bytes (one full row per global_load_lds instr) into a
//   2-deep 32 KB LDS ring (64 KB -> 2 blocks/CU). One __syncthreads per
//   phase (drains DMA + orders waves). B (w1f, L2-resident) goes straight
//   global->VGPR, 2-bank ping-pong; next-phase banks are issued BEFORE the
//   next A-stage so B-waits at phase start never drain the A-stage.
//   A chunks XOR-pre-swizzled at 16B granularity within 128B windows
//   (source side), read back with the same XOR -> conflict-free ds_read_b128.
// LDS overlays after the k-loop: h1 2x4KB @0; z5s @32768; psum @33792.
// ---------------------------------------------------------------------------
__launch_bounds__(128, 1)
__global__ void fused_main(const float* __restrict__ x,
                           const __bf16* __restrict__ w1f,
                           const float* __restrict__ b1,
                           const __bf16* __restrict__ w2f,
                           const float* __restrict__ b2,
                           const float* __restrict__ W3,
                           const float* __restrict__ b3,
                           const float* __restrict__ conv_k,
                           const float* __restrict__ conv_b,
                           const float* __restrict__ bp,
                           const float* __restrict__ head_b,
                           float* __restrict__ out) {
    __shared__ __align__(16) char smem[65536];

    const int tid = threadIdx.x;
    const int w = tid >> 6;      // wave 0/1
    const int l = tid & 63;
    const int r = l & 15;        // fragment col/row index
    const int j = l >> 4;        // fragment k-group
    const int row0 = blockIdx.x * 32;

    // per-lane staging byte offsets: instr i covers block-row rib = 2i+w,
    // lane l holds LDS chunk l <- global chunk (l&~7) | ((l&7)^(rib&7))
    unsigned aOff[16];
#pragma unroll
    for (int i = 0; i < 16; ++i) {
        int rib = i * 2 + w;
        aOff[i] = (unsigned)(row0 + rib) * (IN_DIM * 4)
                + ((unsigned)((l & ~7) | ((l & 7) ^ (rib & 7))) << 4);
    }
    const char* xb = (const char*)x;

#define STAGE(P, BO)                                                          \
    {                                                                         \
        _Pragma("unroll")                                                     \
        for (int i = 0; i < 16; ++i)                                          \
            gld16(xb + aOff[i] + (unsigned)(P) * 1024u,                       \
                  smem + (BO) + ((i * 2 + w) << 10));                         \
    }

    bf16x8 B0[8], B1[8];
#define LOADB(BANK, T)                                                        \
    {                                                                         \
        _Pragma("unroll")                                                     \
        for (int c = 0; c < 8; ++c)                                           \
            BANK[c] = *(const bf16x8*)(w1f + ((size_t)(T) << 12) + (c << 9)   \
                                       + l * 8);                              \
    }

    f32x4 acc[8];
#pragma unroll
    for (int c = 0; c < 8; ++c) acc[c] = (f32x4){0.f, 0.f, 0.f, 0.f};

    // ---- prologue ---------------------------------------------------------
    STAGE(0, 0)
    STAGE(1, 32768)
    LOADB(B0, 0)
    LOADB(B1, 1)
    __syncthreads();

    // ---- 8 phases x 8 ksteps ---------------------------------------------
#pragma unroll 1
    for (int p = 0; p < 8; ++p) {
        const char* ar = smem + ((p & 1) << 15) + ((w * 16 + r) << 10);
#pragma unroll
        for (int t = 0; t < 8; ++t) {
            f32x4 f0 = *(const f32x4*)(ar + (((8 * t + 2 * j)     ^ (r & 7)) << 4));
            f32x4 f1 = *(const f32x4*)(ar + (((8 * t + 2 * j + 1) ^ (r & 7)) << 4));
            bf16x8 Af;
            Af[0] = (__bf16)f0.x; Af[1] = (__bf16)f0.y;
            Af[2] = (__bf16)f0.z; Af[3] = (__bf16)f0.w;
            Af[4] = (__bf16)f1.x; Af[5] = (__bf16)f1.y;
            Af[6] = (__bf16)f1.z; Af[7] = (__bf16)f1.w;
            if ((t & 1) == 0) {
#pragma unroll
                for (int c = 0; c < 8; ++c) acc[c] = mfma16(Af, B0[c], acc[c]);
                if (t < 6) { LOADB(B0, p * 8 + t + 2) }
            } else {
#pragma unroll
                for (int c = 0; c < 8; ++c) acc[c] = mfma16(Af, B1[c], acc[c]);
                if (t < 6) { LOADB(B1, p * 8 + t + 2) }
            }
        }
        __syncthreads();                 // drains this phase's DMA + B loads
        if (p < 7) {
            LOADB(B0, (p + 1) * 8)       // next-phase B banks FIRST (older
            LOADB(B1, (p + 1) * 8 + 1)   //  than the A-stage in vmcnt order)
            __builtin_amdgcn_sched_barrier(0);
        }
        if (p < 6) STAGE(p + 2, (p & 1) << 15)
    }

    // ---- epilogue: + b1, relu, bf16 -> wave-private h1 tile [16][128] -----
    float b1v[8];
#pragma unroll
    for (int c = 0; c < 8; ++c) b1v[c] = b1[c * 16 + r];
    __bf16* hw1 = (__bf16*)(smem + (w << 12));
#pragma unroll
    for (int c = 0; c < 8; ++c)
#pragma unroll
        for (int rr = 0; rr < 4; ++rr)
            hw1[(j * 4 + rr) * NH1 + c * 16 + r] =
                (__bf16)fmaxf(acc[c][rr] + b1v[c], 0.f);

    // ---- stage 2: h2 = relu(h1 @ W2 + b2), wave-private -------------------
    f32x4 acc2[4];
#pragma unroll
    for (int c2 = 0; c2 < 4; ++c2) acc2[c2] = (f32x4){0.f, 0.f, 0.f, 0.f};

#pragma unroll
    for (int kb = 0; kb < 4; ++kb) {
        bf16x8 A = *(const bf16x8*)&hw1[r * NH1 + kb * 32 + j * 8];
#pragma unroll
        for (int c2 = 0; c2 < 4; ++c2) {
            bf16x8 B = *(const bf16x8*)(w2f + (((c2 << 2) + kb) << 9) + l * 8);
            acc2[c2] = mfma16(A, B, acc2[c2]);
        }
    }

    // ---- stage 3: z = h2 @ W3 + b3 ; conv sigmoid -------------------------
    float b2v[4];
#pragma unroll
    for (int c2 = 0; c2 < 4; ++c2) b2v[c2] = b2[c2 * 16 + r];
    float w3l[4][4];
#pragma unroll
    for (int c2 = 0; c2 < 4; ++c2) {
        f32x4 t = *(const f32x4*)&W3[(c2 * 16 + r) * 4];
        w3l[c2][0] = t.x; w3l[c2][1] = t.y; w3l[c2][2] = t.z; w3l[c2][3] = t.w;
    }
    float h2v[4][4];
#pragma unroll
    for (int c2 = 0; c2 < 4; ++c2)
#pragma unroll
        for (int rr = 0; rr < 4; ++rr)
            h2v[c2][rr] = fmaxf(acc2[c2][rr] + b2v[c2], 0.f);

    float pz[4][4];
#pragma unroll
    for (int rr = 0; rr < 4; ++rr)
#pragma unroll
        for (int jj = 0; jj < 4; ++jj) {
            float s = 0.f;
#pragma unroll
            for (int c2 = 0; c2 < 4; ++c2) s = fmaf(h2v[c2][rr], w3l[c2][jj], s);
            pz[rr][jj] = s;
        }
#pragma unroll
    for (int off = 1; off < 16; off <<= 1)
#pragma unroll
        for (int rr = 0; rr < 4; ++rr)
#pragma unroll
            for (int jj = 0; jj < 4; ++jj)
                pz[rr][jj] += __shfl_xor(pz[rr][jj], off, 64);

    const float ck0 = conv_k[0], ck1 = conv_k[1], ck2 = conv_k[2], ck3 = conv_k[3];
    const float cbv = conv_b[0];
    const float b30 = b3[0], b31 = b3[1], b32 = b3[2], b33 = b3[3];
    const float L2E = 1.44269504088896340736f;

    float (*z5s)[8] = (float(*)[8])(smem + 32768);
    float* psum = (float*)(smem + 32768 + 1024);

    if (r == 0) {
#pragma unroll
        for (int rr = 0; rr < 4; ++rr) {
            int rl = w * 16 + (j << 2) + rr;
            float z0 = pz[rr][0] + b30;
            float z1 = pz[rr][1] + b31;
            float z2 = pz[rr][2] + b32;
            float z3 = pz[rr][3] + b33;
            float s = fmaf(z0, ck0, fmaf(z1, ck1, fmaf(z2, ck2, fmaf(z3, ck3, cbv))));
            float sg = 1.f / (1.f + expf(-s));
            float n2 = z0*z0 + z1*z1 + z2*z2 + z3*z3 + sg*sg;
            z5s[rl][0] = 2.f * L2E * z0;
            z5s[rl][1] = 2.f * L2E * z1;
            z5s[rl][2] = 2.f * L2E * z2;
            z5s[rl][3] = 2.f * L2E * z3;
            z5s[rl][4] = 2.f * L2E * sg;
            z5s[rl][5] = -L2E * n2;
        }
    }
    __syncthreads();

    // ---- stage 4: RBF + head (32 rows; (row, quarter) over 128 threads) ---
    const int row = tid & 31;
    const int q = tid >> 5;          // 0..3, each does 256 basis vectors
    f32x4 za = *(const f32x4*)&z5s[row][0];
    float z4s = z5s[row][4];
    float z5c = z5s[row][5];
    const float* bpp = bp + (size_t)q * 256 * 8;
    float accum = 0.f;
#pragma unroll 4
    for (int jb = 0; jb < 256; ++jb) {
        f32x4 q0 = *(const f32x4*)&bpp[jb * 8];
        f32x4 q1 = *(const f32x4*)&bpp[jb * 8 + 4];
        float arg = fmaf(za.x, q0.x,
                    fmaf(za.y, q0.y,
                    fmaf(za.z, q0.z,
                    fmaf(za.w, q0.w,
                    fmaf(z4s, q1.x, z5c)))));
        accum = fmaf(q1.z, exp2f(arg), accum);
    }
    psum[q * 32 + row] = accum;
    __syncthreads();
    if (tid < 32)
        out[blockIdx.x * 32 + tid] =
            psum[tid] + psum[32 + tid] + psum[64 + tid] + psum[96 + tid]
            + head_b[0];
}

// ---------------------------------------------------------------------------
extern "C" void kernel_launch(void* const* d_in, const int* in_sizes, int n_in,
                              void* d_out, int out_size, void* d_ws, size_t ws_size,
                              hipStream_t stream) {
    const float* x     = (const float*)d_in[0];
    const float* W1    = (const float*)d_in[1];
    const float* b1    = (const float*)d_in[2];
    const float* W2    = (const float*)d_in[3];
    const float* b2    = (const float*)d_in[4];
    const float* W3    = (const float*)d_in[5];
    const float* b3    = (const float*)d_in[6];
    const float* ck    = (const float*)d_in[7];
    const float* cb    = (const float*)d_in[8];
    const float* basis = (const float*)d_in[9];
    const float* hwv   = (const float*)d_in[10];
    const float* hb    = (const float*)d_in[11];

    __bf16* w1f = (__bf16*)d_ws;                                 // 524288 B
    __bf16* w2f = (__bf16*)((char*)d_ws + 524288);               // 16384 B
    float*  bpp = (float*)((char*)d_ws + 524288 + 16384);        // 32768 B

    prep_kernel<<<1024, 256, 0, stream>>>(W1, W2, basis, hwv, w1f, w2f, bpp);
    fused_main<<<2048, 128, 0, stream>>>(x, w1f, b1, w2f, b2, W3, b3, ck, cb,
                                         bpp, hb, (float*)d_out);
}